// Round 7
// baseline (267.939 us; speedup 1.0000x reference)
//
#include <hip/hip_runtime.h>

// SimpleNet R9: R8 + 4 N-tiles per iteration (64 px, 8 outer iters).
// Evidence says latency-bound (VALUBusy fell 91->86 as time improved; chain-
// shortening removals outpaid trans removals; true reg footprint ~110 incl
// AGPR A-frags -> ~3 waves/SIMD). Widening to 4 independent MFMA->act chains
// per layer doubles intra-wave ILP; instruction count per pixel unchanged.
//
//   h = tanh(W_in[25x3] x); 6x: h = tanh(W[25x25] h); out = sigmoid(W_out[3x25] h)
// Layers as D[m][n] = A[m][k]*B[k][n], mfma_f32_16x16x32_f16, 2 M-tiles,
// 4 N-tiles (64 px/wave-iter), K=32. B operand carries r = rcp(exp2(a)+1);
// A' = -2*scale*W with bias column sum_c(W)*scale at k=7 (mu-row 19 = pad),
// B pad slot (j=7 / d1.w) packs constant 1.0.
//
// Relabeling: B element j of lane-group g = physical row mu(8g+j); physical
// rows carry logical channels via ch_map (pads at rows 19,23,27,28,29,30,31).
// Scales: hidden/input *2*log2e (r-domain tanh), output *-log2e (sigmoid=r).

#define HW_PIX (1024 * 1024)
#define NPIX   (4 * HW_PIX)
#define HID    25
#define DEPTH  6

#define TANH_SCALE 2.8853900817779268f    // 2*log2(e)
#define SIG_SCALE  (-1.4426950408889634f) // -log2(e)

typedef __fp16 h8 __attribute__((ext_vector_type(8)));
typedef __fp16 hpk2 __attribute__((ext_vector_type(2)));
typedef float f32x4 __attribute__((ext_vector_type(4)));

// ws layout: [0,768) h8 frags: hidden A[(l*2+t)*64+q]; [768,832) h8: A_out[q];
// then (byte 13312) float Winp[32][3].
#define WS_WINP_BYTE 13312

__device__ __forceinline__ int mu_map(int k) {
    int g = k >> 3, j = k & 7;
    return (j < 4) ? (4 * g + j) : (16 + 4 * g + (j & 3));
}

// physical row -> logical channel; -1 = pad.
__device__ __forceinline__ int ch_map(int m) {
    if (m <= 18) return m;
    if (m >= 20 && m <= 22) return m - 1;
    if (m >= 24 && m <= 26) return m - 2;
    return -1;
}

__global__ __launch_bounds__(256) void prep_kernel(
    const float* __restrict__ w_in, const float* __restrict__ ws,
    const float* __restrict__ w_out, __fp16* __restrict__ wsA,
    float* __restrict__ winp)
{
    int tid = threadIdx.x;
    // hidden A-frags: 12 combos (layer l, tile t) x 64 lanes
    // A'[m,c] = -2*scale*W[m,c]; A'[m, k=7] = scale * sum_c W[m,c] (bias)
    for (int u = tid; u < 12 * 64; u += 256) {
        int q = u & 63, combo = u >> 6;
        int l = combo >> 1, t = combo & 1;
        int m = t * 16 + (q & 15);           // physical out row
        int cm = ch_map(m);                  // logical out channel
        for (int j = 0; j < 8; ++j) {
            int k = (q >> 4) * 8 + j;        // physical k column (0..31)
            float v = 0.0f;
            if (cm >= 0) {
                if (k == 7) {                // bias column (mu=19, pad row)
                    float s = 0.0f;
                    for (int c = 0; c < HID; ++c) s += ws[(l * HID + cm) * HID + c];
                    v = s * TANH_SCALE;
                } else {
                    int cc = ch_map(mu_map(k));
                    if (cc >= 0) v = -2.0f * TANH_SCALE * ws[(l * HID + cm) * HID + cc];
                }
            }
            wsA[u * 8 + j] = (__fp16)v;
        }
    }
    // output A-frag (rows 0..2 = out channels), same transform with SIG_SCALE
    if (tid < 64) {
        int q = tid, m = q & 15;
        for (int j = 0; j < 8; ++j) {
            int k = (q >> 4) * 8 + j;
            float v = 0.0f;
            if (m < 3) {
                if (k == 7) {
                    float s = 0.0f;
                    for (int c = 0; c < HID; ++c) s += w_out[m * HID + c];
                    v = s * SIG_SCALE;
                } else {
                    int cc = ch_map(mu_map(k));
                    if (cc >= 0) v = -2.0f * SIG_SCALE * w_out[m * HID + cc];
                }
            }
            wsA[(12 * 64 + q) * 8 + j] = (__fp16)v;
        }
    }
    // input weights, mu-ordered rows: winp[k][c] = w_in[ch(mu(k))][c] * scale
    // (input layer consumes raw x: no affine absorption here)
    if (tid < 32) {
        int k = tid, c = ch_map(mu_map(k));
        for (int ci = 0; ci < 3; ++ci)
            winp[k * 3 + ci] = (c >= 0) ? w_in[c * 3 + ci] * TANH_SCALE : 0.0f;
    }
}

// r = rcp(exp2(a)+1): 2 trans + 1 add, 3-deep chain.
__device__ __forceinline__ float ract(float a) {
    return __builtin_amdgcn_rcpf(__builtin_amdgcn_exp2f(a) + 1.0f);
}

__global__ __launch_bounds__(256, 1) void simplenet_kernel(
    const float* __restrict__ x,     // [4,3,1024,1024]
    const h8* __restrict__ wsA,      // packed A fragments
    const float* __restrict__ winp,  // [32][3] mu-ordered, scaled
    float* __restrict__ out)         // [4,3,1024,1024]
{
    const int lane = threadIdx.x & 63;
    const int wgid = blockIdx.x * 4 + (threadIdx.x >> 6);
    const int g = lane >> 4, col = lane & 15;

    // hoist all weight fragments into registers (reused over 8 iterations)
    h8 A[12];
#pragma unroll
    for (int i = 0; i < 12; ++i) A[i] = wsA[i * 64 + lane];
    h8 Aout = wsA[12 * 64 + lane];

    // input-layer rows this lane computes: mu-ordered rows 8g..8g+7, 3 floats each
    float wi[24];
    {
        const f32x4* wp4 = (const f32x4*)(winp + 8 * g * 3);  // 24 floats, 16B-aligned
#pragma unroll
        for (int i = 0; i < 6; ++i) {
            f32x4 v = wp4[i];
            wi[i * 4 + 0] = v.x; wi[i * 4 + 1] = v.y; wi[i * 4 + 2] = v.z; wi[i * 4 + 3] = v.w;
        }
    }

    const int pbase = wgid * 512;           // 512 consecutive pixels per wave
    const int b = pbase >> 20;              // image index (512 | 2^20: no straddle)
    const int hwb = pbase & (HW_PIX - 1);
    const float* xb = x + (size_t)b * 3 * HW_PIX;
    float* ob = out + (size_t)b * 3 * HW_PIX;

    for (int it = 0; it < 8; ++it) {
        const int hw0 = hwb + it * 64;

        // ---- input layer: 4 n-tiles; lane computes r for j=0..6; j=7 = 1.0 ----
        h8 B[4];
#pragma unroll
        for (int n = 0; n < 4; ++n) {
            const int hw = hw0 + n * 16 + col;
            float x0 = xb[0 * HW_PIX + hw];
            float x1 = xb[1 * HW_PIX + hw];
            float x2 = xb[2 * HW_PIX + hw];
            float acc[7];
#pragma unroll
            for (int j = 0; j < 7; ++j) {
                float a = wi[j * 3 + 0] * x0;
                a = fmaf(wi[j * 3 + 1], x1, a);
                acc[j] = fmaf(wi[j * 3 + 2], x2, a);
            }
            union { h8 v; hpk2 p[4]; } u;
            u.p[0] = __builtin_amdgcn_cvt_pkrtz(ract(acc[0]), ract(acc[1]));
            u.p[1] = __builtin_amdgcn_cvt_pkrtz(ract(acc[2]), ract(acc[3]));
            u.p[2] = __builtin_amdgcn_cvt_pkrtz(ract(acc[4]), ract(acc[5]));
            u.p[3] = __builtin_amdgcn_cvt_pkrtz(ract(acc[6]), 1.0f);  // bias slot
            B[n] = u.v;
        }

        // ---- 6 hidden layers: 2 M-tiles x 4 N-tiles MFMA, direct-rcp r ----
        // 4 independent MFMA->act->repack chains per layer = the ILP lever.
#pragma unroll
        for (int l = 0; l < 6; ++l) {
#pragma unroll
            for (int n = 0; n < 4; ++n) {
                f32x4 zero = {0.0f, 0.0f, 0.0f, 0.0f};
                f32x4 d0 = __builtin_amdgcn_mfma_f32_16x16x32_f16(A[l * 2 + 0], B[n], zero, 0, 0, 0);
                f32x4 d1 = __builtin_amdgcn_mfma_f32_16x16x32_f16(A[l * 2 + 1], B[n], zero, 0, 0, 0);
                // D tile t reg r = phys row (t*16 + 4g + r); next B elem j:
                //   j<4 -> tile0 reg j ; j>=4 -> tile1 reg j-4.
                // d1.w = rows {19,23,27,31} = pad -> bias slot, pack 1.0.
                union { h8 v; hpk2 p[4]; } u;
                u.p[0] = __builtin_amdgcn_cvt_pkrtz(ract(d0.x), ract(d0.y));
                u.p[1] = __builtin_amdgcn_cvt_pkrtz(ract(d0.z), ract(d0.w));
                u.p[2] = __builtin_amdgcn_cvt_pkrtz(ract(d1.x), ract(d1.y));
                u.p[3] = __builtin_amdgcn_cvt_pkrtz(ract(d1.z), 1.0f);
                B[n] = u.v;
            }
        }

        // ---- output layer: sigmoid == r; channels in rows 0..2 (g==0) ----
#pragma unroll
        for (int n = 0; n < 4; ++n) {
            f32x4 zero = {0.0f, 0.0f, 0.0f, 0.0f};
            f32x4 d = __builtin_amdgcn_mfma_f32_16x16x32_f16(Aout, B[n], zero, 0, 0, 0);
            if (g == 0) {
                const int hw = hw0 + n * 16 + col;
                ob[0 * HW_PIX + hw] = ract(d.x);
                ob[1 * HW_PIX + hw] = ract(d.y);
                ob[2 * HW_PIX + hw] = ract(d.z);
            }
        }
    }
}

extern "C" void kernel_launch(void* const* d_in, const int* in_sizes, int n_in,
                              void* d_out, int out_size, void* d_ws, size_t ws_size,
                              hipStream_t stream) {
    const float* x     = (const float*)d_in[0];
    const float* w_in  = (const float*)d_in[1];
    const float* ws    = (const float*)d_in[2];
    const float* w_out = (const float*)d_in[3];
    float* out         = (float*)d_out;

    __fp16* wsA = (__fp16*)d_ws;
    float* winp = (float*)((char*)d_ws + WS_WINP_BYTE);

    hipLaunchKernelGGL(prep_kernel, dim3(1), dim3(256), 0, stream,
                       w_in, ws, w_out, wsA, winp);

    // 8192 waves x 8 iters x 64 px = 4Mi pixels, exact
    hipLaunchKernelGGL(simplenet_kernel, dim3(2048), dim3(256), 0, stream,
                       x, (const h8*)d_ws, winp, out);
}

// Round 8
// 257.345 us; speedup vs baseline: 1.0412x; 1.0412x over previous
//
#include <hip/hip_runtime.h>

// SimpleNet R10: R9 + input layer moved onto MFMA + f32x4-vectorized "+1".
// Model (fit from R6b/R7/R8 deltas): throughput-bound; regular VALU ~4.7
// effective cyc, trans ~12.6; trans count is near algorithmic floor, so the
// remaining lever is deleting regular instrs. The 25x3 input layer's 84
// FMA/iter is matmul-shaped -> MFMA (pipe at ~12% util). A_in has only
// k=0..2 columns nonzero; lanes q>=16 carry zero frags so every lane packs
// (x0,x1),(x2,0),0,0 uniformly (their products hit zero weights). Input D
// layout == hidden D layout -> same act/pack path incl. bias slot.
//
//   h = tanh(W_in[25x3] x); 6x: h = tanh(W[25x25] h); out = sigmoid(W_out[3x25] h)
// Layers as D[m][n] = A[m][k]*B[k][n], mfma_f32_16x16x32_f16, 2 M-tiles,
// 4 N-tiles (64 px/wave-iter), K=32. B operand carries r = rcp(exp2(a)+1);
// A' = -2*scale*W with bias column sum_c(W)*scale at k=7 (mu-row 19 = pad),
// B pad slot (j=7 / d1.w) packs constant 1.0.
//
// Relabeling: B element j of lane-group g = physical row mu(8g+j); physical
// rows carry logical channels via ch_map (pads at rows 19,23,27,28,29,30,31).
// Scales: hidden/input *2*log2e (r-domain tanh), output *-log2e (sigmoid=r).

#define HW_PIX (1024 * 1024)
#define NPIX   (4 * HW_PIX)
#define HID    25
#define DEPTH  6

#define TANH_SCALE 2.8853900817779268f    // 2*log2(e)
#define SIG_SCALE  (-1.4426950408889634f) // -log2(e)

typedef __fp16 h8 __attribute__((ext_vector_type(8)));
typedef __fp16 hpk2 __attribute__((ext_vector_type(2)));
typedef float f32x4 __attribute__((ext_vector_type(4)));

// ws layout (h8 units): [0,768) hidden A[(l*2+t)*64+q]; [768,832) A_out[q];
// [832,864) A_in[t*16+q] (2 tiles x 16 lanes; lanes q>=16 are all-zero frags,
// not stored).

__device__ __forceinline__ int mu_map(int k) {
    int g = k >> 3, j = k & 7;
    return (j < 4) ? (4 * g + j) : (16 + 4 * g + (j & 3));
}

// physical row -> logical channel; -1 = pad.
__device__ __forceinline__ int ch_map(int m) {
    if (m <= 18) return m;
    if (m >= 20 && m <= 22) return m - 1;
    if (m >= 24 && m <= 26) return m - 2;
    return -1;
}

__global__ __launch_bounds__(256) void prep_kernel(
    const float* __restrict__ w_in, const float* __restrict__ ws,
    const float* __restrict__ w_out, __fp16* __restrict__ wsA)
{
    int tid = threadIdx.x;
    // hidden A-frags: 12 combos (layer l, tile t) x 64 lanes
    // A'[m,c] = -2*scale*W[m,c]; A'[m, k=7] = scale * sum_c W[m,c] (bias)
    for (int u = tid; u < 12 * 64; u += 256) {
        int q = u & 63, combo = u >> 6;
        int l = combo >> 1, t = combo & 1;
        int m = t * 16 + (q & 15);           // physical out row
        int cm = ch_map(m);                  // logical out channel
        for (int j = 0; j < 8; ++j) {
            int k = (q >> 4) * 8 + j;        // physical k column (0..31)
            float v = 0.0f;
            if (cm >= 0) {
                if (k == 7) {                // bias column (mu=19, pad row)
                    float s = 0.0f;
                    for (int c = 0; c < HID; ++c) s += ws[(l * HID + cm) * HID + c];
                    v = s * TANH_SCALE;
                } else {
                    int cc = ch_map(mu_map(k));
                    if (cc >= 0) v = -2.0f * TANH_SCALE * ws[(l * HID + cm) * HID + cc];
                }
            }
            wsA[u * 8 + j] = (__fp16)v;
        }
    }
    // output A-frag (rows 0..2 = out channels), same transform with SIG_SCALE
    if (tid < 64) {
        int q = tid, m = q & 15;
        for (int j = 0; j < 8; ++j) {
            int k = (q >> 4) * 8 + j;
            float v = 0.0f;
            if (m < 3) {
                if (k == 7) {
                    float s = 0.0f;
                    for (int c = 0; c < HID; ++c) s += w_out[m * HID + c];
                    v = s * SIG_SCALE;
                } else {
                    int cc = ch_map(mu_map(k));
                    if (cc >= 0) v = -2.0f * SIG_SCALE * w_out[m * HID + cc];
                }
            }
            wsA[(12 * 64 + q) * 8 + j] = (__fp16)v;
        }
    }
    // input A-frags: only lanes q<16 (k-base 0) nonzero; cols k=0..2 = input
    // channels, no bias. Row m = t*16+q carries logical channel ch_map(m).
    if (tid < 32) {
        int t = tid >> 4, q = tid & 15;
        int m = t * 16 + q;
        int cm = ch_map(m);
        for (int j = 0; j < 8; ++j) {
            float v = (cm >= 0 && j < 3) ? w_in[cm * 3 + j] * TANH_SCALE : 0.0f;
            wsA[(13 * 64 + t * 16 + q) * 8 + j] = (__fp16)v;
        }
    }
}

// r = rcp(exp2(a)+1): 2 trans + 1 add, 3-deep chain.
__device__ __forceinline__ float ract(float a) {
    return __builtin_amdgcn_rcpf(__builtin_amdgcn_exp2f(a) + 1.0f);
}

// activation + repack for one (d0,d1) MFMA pair; d1.w is the pad/bias slot
// (row all-zero weights -> d1.w == 0, ignored; 1.0 packed for next layer).
__device__ __forceinline__ h8 act_pack(f32x4 d0, f32x4 d1) {
    f32x4 e0, e1;
    e0.x = __builtin_amdgcn_exp2f(d0.x);
    e0.y = __builtin_amdgcn_exp2f(d0.y);
    e0.z = __builtin_amdgcn_exp2f(d0.z);
    e0.w = __builtin_amdgcn_exp2f(d0.w);
    e1.x = __builtin_amdgcn_exp2f(d1.x);
    e1.y = __builtin_amdgcn_exp2f(d1.y);
    e1.z = __builtin_amdgcn_exp2f(d1.z);
    e1.w = 1.0f;
    f32x4 t0 = e0 + 1.0f;   // vector add: candidate for v_pk_add_f32
    f32x4 t1 = e1 + 1.0f;
    union { h8 v; hpk2 p[4]; } u;
    u.p[0] = __builtin_amdgcn_cvt_pkrtz(__builtin_amdgcn_rcpf(t0.x), __builtin_amdgcn_rcpf(t0.y));
    u.p[1] = __builtin_amdgcn_cvt_pkrtz(__builtin_amdgcn_rcpf(t0.z), __builtin_amdgcn_rcpf(t0.w));
    u.p[2] = __builtin_amdgcn_cvt_pkrtz(__builtin_amdgcn_rcpf(t1.x), __builtin_amdgcn_rcpf(t1.y));
    u.p[3] = __builtin_amdgcn_cvt_pkrtz(__builtin_amdgcn_rcpf(t1.z), 1.0f);  // bias slot
    return u.v;
}

__global__ __launch_bounds__(256, 1) void simplenet_kernel(
    const float* __restrict__ x,     // [4,3,1024,1024]
    const h8* __restrict__ wsA,      // packed A fragments
    float* __restrict__ out)         // [4,3,1024,1024]
{
    const int lane = threadIdx.x & 63;
    const int wgid = blockIdx.x * 4 + (threadIdx.x >> 6);
    const int g = lane >> 4, col = lane & 15;

    // hoist all weight fragments into registers (reused over 8 iterations)
    h8 A[12];
#pragma unroll
    for (int i = 0; i < 12; ++i) A[i] = wsA[i * 64 + lane];
    h8 Aout = wsA[12 * 64 + lane];
    h8 zero8 = {};
    h8 Ain0 = (lane < 16) ? wsA[13 * 64 + lane]      : zero8;
    h8 Ain1 = (lane < 16) ? wsA[13 * 64 + 16 + lane] : zero8;

    const int pbase = wgid * 512;           // 512 consecutive pixels per wave
    const int b = pbase >> 20;              // image index (512 | 2^20: no straddle)
    const int hwb = pbase & (HW_PIX - 1);
    const float* xb = x + (size_t)b * 3 * HW_PIX;
    float* ob = out + (size_t)b * 3 * HW_PIX;

    for (int it = 0; it < 8; ++it) {
        const int hw0 = hwb + it * 64;

        // ---- input layer via MFMA: pack (x0,x1),(x2,0),0,0; A_in cols 0..2 ----
        h8 B[4];
#pragma unroll
        for (int n = 0; n < 4; ++n) {
            const int hw = hw0 + n * 16 + col;
            float x0 = xb[0 * HW_PIX + hw];
            float x1 = xb[1 * HW_PIX + hw];
            float x2 = xb[2 * HW_PIX + hw];
            union { h8 v; hpk2 p[4]; } ux;
            ux.p[0] = __builtin_amdgcn_cvt_pkrtz(x0, x1);
            ux.p[1] = __builtin_amdgcn_cvt_pkrtz(x2, 0.0f);
            ux.p[2] = hpk2{};
            ux.p[3] = hpk2{};
            f32x4 zc = {0.0f, 0.0f, 0.0f, 0.0f};
            f32x4 d0 = __builtin_amdgcn_mfma_f32_16x16x32_f16(Ain0, ux.v, zc, 0, 0, 0);
            f32x4 d1 = __builtin_amdgcn_mfma_f32_16x16x32_f16(Ain1, ux.v, zc, 0, 0, 0);
            B[n] = act_pack(d0, d1);
        }

        // ---- 6 hidden layers: 2 M-tiles x 4 N-tiles MFMA, direct-rcp r ----
#pragma unroll
        for (int l = 0; l < 6; ++l) {
#pragma unroll
            for (int n = 0; n < 4; ++n) {
                f32x4 zc = {0.0f, 0.0f, 0.0f, 0.0f};
                f32x4 d0 = __builtin_amdgcn_mfma_f32_16x16x32_f16(A[l * 2 + 0], B[n], zc, 0, 0, 0);
                f32x4 d1 = __builtin_amdgcn_mfma_f32_16x16x32_f16(A[l * 2 + 1], B[n], zc, 0, 0, 0);
                // D tile t reg r = phys row (t*16 + 4g + r); next B elem j:
                //   j<4 -> tile0 reg j ; j>=4 -> tile1 reg j-4.
                // d1.w = rows {19,23,27,31} = pad -> bias slot, pack 1.0.
                B[n] = act_pack(d0, d1);
            }
        }

        // ---- output layer: sigmoid == r; channels in rows 0..2 (g==0) ----
#pragma unroll
        for (int n = 0; n < 4; ++n) {
            f32x4 zc = {0.0f, 0.0f, 0.0f, 0.0f};
            f32x4 d = __builtin_amdgcn_mfma_f32_16x16x32_f16(Aout, B[n], zc, 0, 0, 0);
            if (g == 0) {
                const int hw = hw0 + n * 16 + col;
                ob[0 * HW_PIX + hw] = ract(d.x);
                ob[1 * HW_PIX + hw] = ract(d.y);
                ob[2 * HW_PIX + hw] = ract(d.z);
            }
        }
    }
}

extern "C" void kernel_launch(void* const* d_in, const int* in_sizes, int n_in,
                              void* d_out, int out_size, void* d_ws, size_t ws_size,
                              hipStream_t stream) {
    const float* x     = (const float*)d_in[0];
    const float* w_in  = (const float*)d_in[1];
    const float* ws    = (const float*)d_in[2];
    const float* w_out = (const float*)d_in[3];
    float* out         = (float*)d_out;

    __fp16* wsA = (__fp16*)d_ws;

    hipLaunchKernelGGL(prep_kernel, dim3(1), dim3(256), 0, stream,
                       w_in, ws, w_out, wsA);

    // 8192 waves x 8 iters x 64 px = 4Mi pixels, exact
    hipLaunchKernelGGL(simplenet_kernel, dim3(2048), dim3(256), 0, stream,
                       x, (const h8*)d_ws, out);
}

// Round 9
// 237.265 us; speedup vs baseline: 1.1293x; 1.0846x over previous
//
#include <hip/hip_runtime.h>

// SimpleNet R11: R10 + A-fragments in LDS (shared per block) to raise
// occupancy. Model from R6b-R10 (4-experiment fit): cost = 4.7*reg + 13*trans
// cyc/iter; both coefficients are ~2x their issue floors (2, 8) -> stall-
// inflated. Suspect: A-frags in AGPRs (VGPR_Count=68 can't hold them) ->
// ~124 regs/lane -> <=4 waves/SIMD. Moving the 12 hidden A-frags + spares
// to LDS (13.5 KiB, broadcast-read by all 4 waves) drops footprint to ~70
// and __launch_bounds__(256,4) guarantees >=4 waves/SIMD; more TLP should
// compress the stall-inflated coefficients. Cost: +12 ds_read_b128/iter.
//
//   h = tanh(W_in[25x3] x); 6x: h = tanh(W[25x25] h); out = sigmoid(W_out[3x25] h)
// Layers as D[m][n] = A[m][k]*B[k][n], mfma_f32_16x16x32_f16, 2 M-tiles,
// 4 N-tiles (64 px/wave-iter), K=32. B operand carries r = rcp(exp2(a)+1);
// A' = -2*scale*W with bias column sum_c(W)*scale at k=7 (mu-row 19 = pad),
// B pad slot (j=7 / d1.w) packs constant 1.0. Input layer on MFMA (A_in
// cols 0..2; lanes q>=16 zero frags; packs (x0,x1),(x2,0),0,0 uniformly).
//
// Relabeling: B element j of lane-group g = physical row mu(8g+j); physical
// rows carry logical channels via ch_map (pads at rows 19,23,27,28,29,30,31).
// Scales: hidden/input *2*log2e (r-domain tanh), output *-log2e (sigmoid=r).

#define HW_PIX (1024 * 1024)
#define NPIX   (4 * HW_PIX)
#define HID    25
#define DEPTH  6

#define TANH_SCALE 2.8853900817779268f    // 2*log2(e)
#define SIG_SCALE  (-1.4426950408889634f) // -log2(e)

typedef __fp16 h8 __attribute__((ext_vector_type(8)));
typedef __fp16 hpk2 __attribute__((ext_vector_type(2)));
typedef float f32x4 __attribute__((ext_vector_type(4)));

// ws layout (h8 units): [0,768) hidden A[(l*2+t)*64+q]; [768,832) A_out[q];
// [832,864) A_in[t*16+q] (2 tiles x 16 lanes; q>=16 lanes are zero frags).
#define WS_H8_TOTAL (13 * 64 + 32)

__device__ __forceinline__ int mu_map(int k) {
    int g = k >> 3, j = k & 7;
    return (j < 4) ? (4 * g + j) : (16 + 4 * g + (j & 3));
}

// physical row -> logical channel; -1 = pad.
__device__ __forceinline__ int ch_map(int m) {
    if (m <= 18) return m;
    if (m >= 20 && m <= 22) return m - 1;
    if (m >= 24 && m <= 26) return m - 2;
    return -1;
}

__global__ __launch_bounds__(256) void prep_kernel(
    const float* __restrict__ w_in, const float* __restrict__ ws,
    const float* __restrict__ w_out, __fp16* __restrict__ wsA)
{
    int tid = threadIdx.x;
    // hidden A-frags: 12 combos (layer l, tile t) x 64 lanes
    // A'[m,c] = -2*scale*W[m,c]; A'[m, k=7] = scale * sum_c W[m,c] (bias)
    for (int u = tid; u < 12 * 64; u += 256) {
        int q = u & 63, combo = u >> 6;
        int l = combo >> 1, t = combo & 1;
        int m = t * 16 + (q & 15);           // physical out row
        int cm = ch_map(m);                  // logical out channel
        for (int j = 0; j < 8; ++j) {
            int k = (q >> 4) * 8 + j;        // physical k column (0..31)
            float v = 0.0f;
            if (cm >= 0) {
                if (k == 7) {                // bias column (mu=19, pad row)
                    float s = 0.0f;
                    for (int c = 0; c < HID; ++c) s += ws[(l * HID + cm) * HID + c];
                    v = s * TANH_SCALE;
                } else {
                    int cc = ch_map(mu_map(k));
                    if (cc >= 0) v = -2.0f * TANH_SCALE * ws[(l * HID + cm) * HID + cc];
                }
            }
            wsA[u * 8 + j] = (__fp16)v;
        }
    }
    // output A-frag (rows 0..2 = out channels), same transform with SIG_SCALE
    if (tid < 64) {
        int q = tid, m = q & 15;
        for (int j = 0; j < 8; ++j) {
            int k = (q >> 4) * 8 + j;
            float v = 0.0f;
            if (m < 3) {
                if (k == 7) {
                    float s = 0.0f;
                    for (int c = 0; c < HID; ++c) s += w_out[m * HID + c];
                    v = s * SIG_SCALE;
                } else {
                    int cc = ch_map(mu_map(k));
                    if (cc >= 0) v = -2.0f * SIG_SCALE * w_out[m * HID + cc];
                }
            }
            wsA[(12 * 64 + q) * 8 + j] = (__fp16)v;
        }
    }
    // input A-frags: only lanes q<16 (k-base 0) nonzero; cols k=0..2 = input
    // channels, no bias. Row m = t*16+q carries logical channel ch_map(m).
    if (tid < 32) {
        int t = tid >> 4, q = tid & 15;
        int m = t * 16 + q;
        int cm = ch_map(m);
        for (int j = 0; j < 8; ++j) {
            float v = (cm >= 0 && j < 3) ? w_in[cm * 3 + j] * TANH_SCALE : 0.0f;
            wsA[(13 * 64 + t * 16 + q) * 8 + j] = (__fp16)v;
        }
    }
}

// r = rcp(exp2(a)+1): 2 trans + 1 add, 3-deep chain.
__device__ __forceinline__ float ract(float a) {
    return __builtin_amdgcn_rcpf(__builtin_amdgcn_exp2f(a) + 1.0f);
}

// activation + repack for one (d0,d1) MFMA pair; d1.w is the pad/bias slot.
__device__ __forceinline__ h8 act_pack(f32x4 d0, f32x4 d1) {
    f32x4 e0, e1;
    e0.x = __builtin_amdgcn_exp2f(d0.x);
    e0.y = __builtin_amdgcn_exp2f(d0.y);
    e0.z = __builtin_amdgcn_exp2f(d0.z);
    e0.w = __builtin_amdgcn_exp2f(d0.w);
    e1.x = __builtin_amdgcn_exp2f(d1.x);
    e1.y = __builtin_amdgcn_exp2f(d1.y);
    e1.z = __builtin_amdgcn_exp2f(d1.z);
    e1.w = 1.0f;
    f32x4 t0 = e0 + 1.0f;   // vector adds: candidate for v_pk_add_f32
    f32x4 t1 = e1 + 1.0f;
    union { h8 v; hpk2 p[4]; } u;
    u.p[0] = __builtin_amdgcn_cvt_pkrtz(__builtin_amdgcn_rcpf(t0.x), __builtin_amdgcn_rcpf(t0.y));
    u.p[1] = __builtin_amdgcn_cvt_pkrtz(__builtin_amdgcn_rcpf(t0.z), __builtin_amdgcn_rcpf(t0.w));
    u.p[2] = __builtin_amdgcn_cvt_pkrtz(__builtin_amdgcn_rcpf(t1.x), __builtin_amdgcn_rcpf(t1.y));
    u.p[3] = __builtin_amdgcn_cvt_pkrtz(__builtin_amdgcn_rcpf(t1.z), 1.0f);  // bias slot
    return u.v;
}

__global__ __launch_bounds__(256, 4) void simplenet_kernel(
    const float* __restrict__ x,     // [4,3,1024,1024]
    const h8* __restrict__ wsA,      // packed A fragments (global)
    float* __restrict__ out)         // [4,3,1024,1024]
{
    __shared__ h8 sA[WS_H8_TOTAL];   // 13.5 KiB: shared by all 4 waves

    const int tid = threadIdx.x;
    const int lane = tid & 63;
    const int wgid = blockIdx.x * 4 + (tid >> 6);
    const int g = lane >> 4, col = lane & 15;

    // cooperative stage of all A fragments into LDS (one-time)
    for (int i = tid; i < WS_H8_TOTAL; i += 256) sA[i] = wsA[i];
    __syncthreads();

    // small frags stay in registers: Aout (4 regs) + Ain (8 regs)
    h8 zero8 = {};
    h8 Aout = sA[12 * 64 + lane];
    h8 Ain0 = (lane < 16) ? sA[13 * 64 + lane]      : zero8;
    h8 Ain1 = (lane < 16) ? sA[13 * 64 + 16 + lane] : zero8;

    const int pbase = wgid * 512;           // 512 consecutive pixels per wave
    const int b = pbase >> 20;              // image index (512 | 2^20: no straddle)
    const int hwb = pbase & (HW_PIX - 1);
    const float* xb = x + (size_t)b * 3 * HW_PIX;
    float* ob = out + (size_t)b * 3 * HW_PIX;

    for (int it = 0; it < 8; ++it) {
        const int hw0 = hwb + it * 64;

        // ---- input layer via MFMA: pack (x0,x1),(x2,0),0,0; A_in cols 0..2 ----
        h8 B[4];
#pragma unroll
        for (int n = 0; n < 4; ++n) {
            const int hw = hw0 + n * 16 + col;
            float x0 = xb[0 * HW_PIX + hw];
            float x1 = xb[1 * HW_PIX + hw];
            float x2 = xb[2 * HW_PIX + hw];
            union { h8 v; hpk2 p[4]; } ux;
            ux.p[0] = __builtin_amdgcn_cvt_pkrtz(x0, x1);
            ux.p[1] = __builtin_amdgcn_cvt_pkrtz(x2, 0.0f);
            ux.p[2] = hpk2{};
            ux.p[3] = hpk2{};
            f32x4 zc = {0.0f, 0.0f, 0.0f, 0.0f};
            f32x4 d0 = __builtin_amdgcn_mfma_f32_16x16x32_f16(Ain0, ux.v, zc, 0, 0, 0);
            f32x4 d1 = __builtin_amdgcn_mfma_f32_16x16x32_f16(Ain1, ux.v, zc, 0, 0, 0);
            B[n] = act_pack(d0, d1);
        }

        // ---- 6 hidden layers: A read from LDS (ds_read_b128, CSE'd over n) ----
#pragma unroll
        for (int l = 0; l < 6; ++l) {
            h8 a0 = sA[(l * 2 + 0) * 64 + lane];
            h8 a1 = sA[(l * 2 + 1) * 64 + lane];
#pragma unroll
            for (int n = 0; n < 4; ++n) {
                f32x4 zc = {0.0f, 0.0f, 0.0f, 0.0f};
                f32x4 d0 = __builtin_amdgcn_mfma_f32_16x16x32_f16(a0, B[n], zc, 0, 0, 0);
                f32x4 d1 = __builtin_amdgcn_mfma_f32_16x16x32_f16(a1, B[n], zc, 0, 0, 0);
                // D tile t reg r = phys row (t*16 + 4g + r); next B elem j:
                //   j<4 -> tile0 reg j ; j>=4 -> tile1 reg j-4.
                // d1.w = rows {19,23,27,31} = pad -> bias slot, pack 1.0.
                B[n] = act_pack(d0, d1);
            }
        }

        // ---- output layer: sigmoid == r; channels in rows 0..2 (g==0) ----
#pragma unroll
        for (int n = 0; n < 4; ++n) {
            f32x4 zc = {0.0f, 0.0f, 0.0f, 0.0f};
            f32x4 d = __builtin_amdgcn_mfma_f32_16x16x32_f16(Aout, B[n], zc, 0, 0, 0);
            if (g == 0) {
                const int hw = hw0 + n * 16 + col;
                ob[0 * HW_PIX + hw] = ract(d.x);
                ob[1 * HW_PIX + hw] = ract(d.y);
                ob[2 * HW_PIX + hw] = ract(d.z);
            }
        }
    }
}

extern "C" void kernel_launch(void* const* d_in, const int* in_sizes, int n_in,
                              void* d_out, int out_size, void* d_ws, size_t ws_size,
                              hipStream_t stream) {
    const float* x     = (const float*)d_in[0];
    const float* w_in  = (const float*)d_in[1];
    const float* ws    = (const float*)d_in[2];
    const float* w_out = (const float*)d_in[3];
    float* out         = (float*)d_out;

    __fp16* wsA = (__fp16*)d_ws;

    hipLaunchKernelGGL(prep_kernel, dim3(1), dim3(256), 0, stream,
                       w_in, ws, w_out, wsA);

    // 8192 waves x 8 iters x 64 px = 4Mi pixels, exact
    hipLaunchKernelGGL(simplenet_kernel, dim3(2048), dim3(256), 0, stream,
                       x, (const h8*)d_ws, out);
}